// Round 4
// baseline (976.375 us; speedup 1.0000x reference)
//
#include <hip/hip_runtime.h>

#define H    64
#define TT   1024
#define MB   8      // batch rows per workgroup
#define NW   512    // 8 waves
#define NWG  256
#define GSP  584    // gate buffer row stride (floats); 584 % 32 == 8; 16B-aligned rows
#define HRUS 144    // h array row stride in ushorts (288 B = 72 dwords; 72 % 32 == 8)

typedef float  f32x4  __attribute__((ext_vector_type(4)));
typedef __bf16 bf16x8 __attribute__((ext_vector_type(8)));

__device__ __forceinline__ unsigned short bf16_rne(float f) {
    unsigned u = __float_as_uint(f);
    u += 0x7FFFu + ((u >> 16) & 1u);
    return (unsigned short)(u >> 16);
}
__device__ __forceinline__ float fast_sigmoid(float x) {
    return __builtin_amdgcn_rcpf(1.0f + __expf(-x));
}
__device__ __forceinline__ float fast_tanh(float x) {
    float xx = fminf(fmaxf(x, -15.0f), 15.0f);
    float e  = __expf(2.0f * xx);
    return (e - 1.0f) * __builtin_amdgcn_rcpf(e + 1.0f);
}

// Operand-swapped MFMA:  D = W · h^T   (A = weight frag, B = h frag)
//   D[row=gatecol within tile][col=batch]; lane(q=lane>>4, r=lane&15) holds
//   rows 16n+4q+k (k=0..3, contiguous!), col r  ->  ONE b128 store per tile.
// B cols 0-7 = h0 batches, 8-15 = h1 batches. Tiles n<24 (gh0,gx1) consume h0
//   -> store cols r<8; tiles 24-35 (gh1) consume h1 -> store cols r>=8 (to batch r-8).
// gA[batch][584]: cols [0,192)=gh0, [192,384)=gx1, [384,576)=gh1; gate col of tile n = 16n.
// hA: 16 rows x 288B: rows 0-7 h0, 8-15 h1; per row: 64 us hi | 64 us lo | 16 pad.
//   Row stride 72 dwords (==8 mod 32) staggers banks -> <=2-way on all h reads/writes.
// 40 tiles, 5/wave (tiles 36-39 dummy on wave 7: MFMA issued, stores suppressed).
// Split-bf16: v*w ~= whi*hhi + whi*hlo + wlo*hhi (6 MFMAs per tile over 2 K-chunks).
__global__ __launch_bounds__(NW, 2) void gru_mfma3(
    const float* __restrict__ x,
    const float* __restrict__ w_ih0, const float* __restrict__ w_hh0,
    const float* __restrict__ b_ih0, const float* __restrict__ b_hh0,
    const float* __restrict__ w_ih1, const float* __restrict__ w_hh1,
    const float* __restrict__ b_ih1, const float* __restrict__ b_hh1,
    const float* __restrict__ w_fc,  const float* __restrict__ b_fc,
    float* __restrict__ out)
{
    __shared__ __align__(16) float          xs[MB * TT];     // 32 KB
    __shared__ __align__(16) float          gA[MB * GSP];    // 18.25 KB
    __shared__ __align__(16) unsigned short hA[16 * HRUS];   // 4.5 KB

    const int tid  = threadIdx.x;
    const int wave = tid >> 6;
    const int lane = tid & 63;
    const int r    = lane & 15;        // A row within tile / D col (batch)
    const int q    = lane >> 4;        // k-group / D row-group
    const int b0g  = blockIdx.x * MB;

    for (int i = tid; i < 16*HRUS; i += NW) hA[i] = 0;
    for (int i = tid; i < MB*GSP;  i += NW) gA[i] = 0.0f;

    // stage x: wave w copies batch row b0g+w (coalesced float4)
    {
        const float* xrow = x + (size_t)(b0g + wave) * TT;
        float* xd = xs + wave * TT;
        #pragma unroll
        for (int u = 0; u < 4; ++u) {
            int idx = (u * 64 + lane) * 4;
            *(float4*)(xd + idx) = *(const float4*)(xrow + idx);
        }
    }

    // ---- persistent weight fragments (A operand), uniform 5 tiles/wave ----
    bf16x8 whi[5][2], wlo[5][2];
    int   doff [5];
    bool  wr_ok[5];
    #pragma unroll
    for (int i = 0; i < 5; ++i) {
        const int n = 5 * wave + i;
        const float* W; int gr;
        if      (n < 12) { W = w_hh0; gr = 16 * n; }
        else if (n < 24) { W = w_ih1; gr = 16 * (n - 12); }
        else if (n < 36) { W = w_hh1; gr = 16 * (n - 24); }
        else             { W = w_hh0; gr = 0; }
        #pragma unroll
        for (int c = 0; c < 2; ++c) {
            // lane supplies A[row=r][k], k = 32c + 8q + j  (A row = gate row gr+r)
            const float* wp = W + (gr + r) * H + 32 * c + 8 * q;
            float4 p0 = *(const float4*)wp;
            float4 p1 = *(const float4*)(wp + 4);
            float f[8] = {p0.x,p0.y,p0.z,p0.w,p1.x,p1.y,p1.z,p1.w};
            unsigned short uh[8], ul[8];
            #pragma unroll
            for (int j = 0; j < 8; ++j) {
                unsigned short h16 = bf16_rne(f[j]);
                uh[j] = h16;
                ul[j] = bf16_rne(f[j] - __uint_as_float((unsigned)h16 << 16));
            }
            whi[i][c] = *(const bf16x8*)uh;
            wlo[i][c] = *(const bf16x8*)ul;
        }
        doff [i] = (r & 7) * GSP + 16 * n + 4 * q;
        wr_ok[i] = (n < 36) && ((n < 24) == (r < 8));
    }

    // ---- loop-invariant LDS pointers ----
    // B-frag (h) reads: lane supplies B[k][col=r] = h[r][k], k = 32c+8q+j
    // chunk m = 4c+q at ushort offset 8m within the 64-us hi region; lo at +64.
    const unsigned short* hp0 = hA + r * HRUS + 8 * q;        // c=0 hi
    const unsigned short* hp1 = hA + r * HRUS + 8 * (4 + q);  // c=1 hi
    const unsigned short* hp2 = hp0 + 64;                     // c=0 lo
    const unsigned short* hp3 = hp1 + 64;                     // c=1 lo

    unsigned short* p0h = hA + wave * HRUS + lane;            // h0 hi
    unsigned short* p0l = p0h + 64;                           // h0 lo
    unsigned short* p1h = hA + (wave + 8) * HRUS + lane;      // h1 hi
    unsigned short* p1l = p1h + 64;                           // h1 lo

    const float* gp  = gA + wave * GSP;
    const float* xmy = xs + wave * TT;

    // ---- gate constants (wave = batch, lane = hidden j) ----
    const float wi0r = w_ih0[lane], wi0z = w_ih0[64+lane], wi0n = w_ih0[128+lane];
    const float c0r  = b_ih0[lane]     + b_hh0[lane];
    const float c0z  = b_ih0[64+lane]  + b_hh0[64+lane];
    const float bi0n = b_ih0[128+lane], bh0n = b_hh0[128+lane];
    const float c1r  = b_ih1[lane]     + b_hh1[lane];
    const float c1z  = b_ih1[64+lane]  + b_hh1[64+lane];
    const float bi1n = b_ih1[128+lane], bh1n = b_hh1[128+lane];
    const float wfc  = w_fc[lane];

    float h0reg = 0.0f, h1reg = 0.0f;
    __syncthreads();

    #pragma unroll 1
    for (int t = 0; t < TT; ++t) {
        // ---------------- G phase ----------------
        if (t > 0) {            // layer 1, step t-1
            float xr = gp[192+lane], xz = gp[256+lane], xn = gp[320+lane];
            float hr = gp[384+lane], hz = gp[448+lane], hn = gp[512+lane];
            float rr = fast_sigmoid(xr + hr + c1r);
            float zz = fast_sigmoid(xz + hz + c1z);
            float nn = fast_tanh(xn + bi1n + rr * (hn + bh1n));
            h1reg = fmaf(zz, h1reg - nn, nn);
            unsigned short hh = bf16_rne(h1reg);
            *p1h = hh;
            *p1l = bf16_rne(h1reg - __uint_as_float((unsigned)hh << 16));
        }
        {                        // layer 0, step t
            float xv  = xmy[t];
            float g0r = gp[lane], g0z = gp[64+lane], g0n = gp[128+lane];
            float rr = fast_sigmoid(fmaf(xv, wi0r, c0r) + g0r);
            float zz = fast_sigmoid(fmaf(xv, wi0z, c0z) + g0z);
            float nn = fast_tanh(fmaf(xv, wi0n, bi0n) + rr * (g0n + bh0n));
            h0reg = fmaf(zz, h0reg - nn, nn);
            unsigned short hh = bf16_rne(h0reg);
            *p0h = hh;
            *p0l = bf16_rne(h0reg - __uint_as_float((unsigned)hh << 16));
        }
        __syncthreads();

        // ---------------- M phase ----------------
        {
            bf16x8 hhi0 = *(const bf16x8*)hp0;
            bf16x8 hhi1 = *(const bf16x8*)hp1;
            bf16x8 hlo0 = *(const bf16x8*)hp2;
            bf16x8 hlo1 = *(const bf16x8*)hp3;
            #pragma unroll
            for (int i = 0; i < 5; ++i) {
                f32x4 d = {0.0f, 0.0f, 0.0f, 0.0f};
                d = __builtin_amdgcn_mfma_f32_16x16x32_bf16(whi[i][0], hhi0, d, 0,0,0);
                d = __builtin_amdgcn_mfma_f32_16x16x32_bf16(whi[i][1], hhi1, d, 0,0,0);
                d = __builtin_amdgcn_mfma_f32_16x16x32_bf16(whi[i][0], hlo0, d, 0,0,0);
                d = __builtin_amdgcn_mfma_f32_16x16x32_bf16(whi[i][1], hlo1, d, 0,0,0);
                d = __builtin_amdgcn_mfma_f32_16x16x32_bf16(wlo[i][0], hhi0, d, 0,0,0);
                d = __builtin_amdgcn_mfma_f32_16x16x32_bf16(wlo[i][1], hhi1, d, 0,0,0);
                if (wr_ok[i]) {
                    *(f32x4*)(gA + doff[i]) = d;   // 4 consecutive gate cols, one b128
                }
            }
        }
        __syncthreads();
    }

    // final layer-1 gate (step TT-1)
    {
        float xr = gp[192+lane], xz = gp[256+lane], xn = gp[320+lane];
        float hr = gp[384+lane], hz = gp[448+lane], hn = gp[512+lane];
        float rr = fast_sigmoid(xr + hr + c1r);
        float zz = fast_sigmoid(xz + hz + c1z);
        float nn = fast_tanh(xn + bi1n + rr * (hn + bh1n));
        h1reg = fmaf(zz, h1reg - nn, nn);
    }
    // FC: out[b] = dot(h1, w_fc) + b_fc
    {
        float v = h1reg * wfc;
        #pragma unroll
        for (int s = 32; s > 0; s >>= 1) v += __shfl_xor(v, s, 64);
        if (lane == 0) out[b0g + wave] = v + b_fc[0];
    }
}

extern "C" void kernel_launch(void* const* d_in, const int* in_sizes, int n_in,
                              void* d_out, int out_size, void* d_ws, size_t ws_size,
                              hipStream_t stream) {
    (void)in_sizes; (void)n_in; (void)out_size; (void)d_ws; (void)ws_size;
    gru_mfma3<<<NWG, NW, 0, stream>>>(
        (const float*)d_in[0],
        (const float*)d_in[1], (const float*)d_in[2],
        (const float*)d_in[3], (const float*)d_in[4],
        (const float*)d_in[5], (const float*)d_in[6],
        (const float*)d_in[7], (const float*)d_in[8],
        (const float*)d_in[9], (const float*)d_in[10],
        (float*)d_out);
}